// Round 2
// baseline (690.918 us; speedup 1.0000x reference)
//
#include <hip/hip_runtime.h>
#include <hip/hip_bf16.h>
#include <math.h>

#define DEV __device__ __forceinline__

typedef short bf16x8 __attribute__((ext_vector_type(8)));
typedef float f32x4 __attribute__((ext_vector_type(4)));

// problem constants
static const int Nn = 2048;
static const int DIMd = 512;
static const int Hh = 8;
static const int Dd = 64;

DEV float bf2f(short u) {
    union { unsigned int i; float f; } c;
    c.i = ((unsigned int)(unsigned short)u) << 16;
    return c.f;
}

DEV short f2bf(float f) {
    union { float f; unsigned int i; } c;
    c.f = f;
    unsigned int u = c.i;
    unsigned int r = (u + 0x7fffu + ((u >> 16) & 1u)) >> 16;
    return (short)r;
}

// ---------------------------------------------------------------------------
// K0: transpose + cast f32 [K][N] -> bf16 [N][K]   (weights; coalesced write)
// ---------------------------------------------------------------------------
__global__ void k_transpose_cast(const float* __restrict__ src,
                                 short* __restrict__ dst, int K, int N) {
    int o = blockIdx.x * 256 + threadIdx.x;
    if (o >= K * N) return;
    int n = o / K, k = o - n * K;
    dst[o] = f2bf(src[(size_t)k * N + n]);
}

// ---------------------------------------------------------------------------
// K1: row LayerNorm over DIM=512, f32 in -> bf16 out. One wave per row.
// ---------------------------------------------------------------------------
__global__ __launch_bounds__(256) void k_ln(const float* __restrict__ x,
                                            const float* __restrict__ g,
                                            const float* __restrict__ bta,
                                            short* __restrict__ xn) {
    int row = blockIdx.x * 4 + (threadIdx.x >> 6);
    int lane = threadIdx.x & 63;
    const float* xr = x + (size_t)row * DIMd;
    float4 v0 = ((const float4*)xr)[lane * 2];
    float4 v1 = ((const float4*)xr)[lane * 2 + 1];
    float f[8] = {v0.x, v0.y, v0.z, v0.w, v1.x, v1.y, v1.z, v1.w};
    float s = 0.f, sq = 0.f;
#pragma unroll
    for (int t = 0; t < 8; ++t) { s += f[t]; sq += f[t] * f[t]; }
#pragma unroll
    for (int off = 32; off >= 1; off >>= 1) {
        s += __shfl_xor(s, off);
        sq += __shfl_xor(sq, off);
    }
    float mu = s * (1.0f / 512.0f);
    float var = sq * (1.0f / 512.0f) - mu * mu;
    float rs = rsqrtf(var + 1e-5f);
    bf16x8 o;
#pragma unroll
    for (int t = 0; t < 8; ++t) {
        int c = lane * 8 + t;
        o[t] = f2bf((f[t] - mu) * rs * g[c] + bta[c]);
    }
    *(bf16x8*)(xn + (size_t)row * DIMd + lane * 8) = o;
}

// ---------------------------------------------------------------------------
// Per-wave 16x64 output tile: A [16 rows, K] k-contig, B^T [64 rows, K]
// k-contig. Verified gfx950 16x16x32 bf16 fragment mappings.
// ---------------------------------------------------------------------------
DEV void mfma_tile_16x64(const short* __restrict__ A, int lda,
                         const short* __restrict__ B, int ldb, int K,
                         int lane, f32x4 acc[4]) {
    const short* arow = A + (size_t)(lane & 15) * lda + ((lane >> 4) * 8);
    const short* brow = B + (size_t)(lane & 15) * ldb + ((lane >> 4) * 8);
    for (int k0 = 0; k0 < K; k0 += 32) {
        bf16x8 af = *(const bf16x8*)(arow + k0);
#pragma unroll
        for (int nf = 0; nf < 4; ++nf) {
            bf16x8 bfr = *(const bf16x8*)(brow + (size_t)nf * 16 * ldb + k0);
            acc[nf] = __builtin_amdgcn_mfma_f32_16x16x32_bf16(af, bfr, acc[nf], 0, 0, 0);
        }
    }
}

// ---------------------------------------------------------------------------
// K2: qkv = xn @ w_qkvT^T. M=8192, N=1536, K=512. Scatter epilogue into
// Q[bh][n][64], K[bh][n][64] (k-contig) and Vt[bh][64][n] (j-contig).
// ---------------------------------------------------------------------------
__global__ __launch_bounds__(256) void k_qkv(const short* __restrict__ xn,
                                             const short* __restrict__ wT,
                                             short* __restrict__ Q,
                                             short* __restrict__ Kb,
                                             short* __restrict__ Vt) {
    int i0 = blockIdx.x * 64, n0 = blockIdx.y * 64;
    int w = threadIdx.x >> 6, lane = threadIdx.x & 63;
    f32x4 acc[4] = {};
    const short* A = xn + (size_t)(i0 + w * 16) * DIMd;
    const short* B = wT + (size_t)n0 * DIMd;
    mfma_tile_16x64(A, DIMd, B, DIMd, DIMd, lane, acc);
    int rbase = i0 + w * 16 + ((lane >> 4) * 4);
#pragma unroll
    for (int nf = 0; nf < 4; ++nf) {
#pragma unroll
        for (int r = 0; r < 4; ++r) {
            int row = rbase + r;                // [0,8192)
            int c = n0 + nf * 16 + (lane & 15); // [0,1536)
            short hv = f2bf(acc[nf][r]);
            int b = row >> 11, i = row & 2047;
            int t = c >> 9, rem = c & 511;
            int h = rem >> 6, dd = rem & 63;
            size_t bh = (size_t)(b * Hh + h);
            if (t == 0)      Q [(bh * Nn + i) * Dd + dd] = hv;
            else if (t == 1) Kb[(bh * Nn + i) * Dd + dd] = hv;
            else             Vt[(bh * Dd + dd) * Nn + i] = hv;
        }
    }
}

// ---------------------------------------------------------------------------
// K3: S = Q K^T * scale for an i-chunk. attnC layout [32 bh][ICH][2048].
// ---------------------------------------------------------------------------
__global__ __launch_bounds__(256) void k_scores(const short* __restrict__ Q,
                                                const short* __restrict__ Kb,
                                                short* __restrict__ attnC,
                                                int i0, int ICH) {
    int iblk = blockIdx.x, jblk = blockIdx.y, bh = blockIdx.z;
    int w = threadIdx.x >> 6, lane = threadIdx.x & 63;
    const short* A = Q + ((size_t)bh * Nn + i0 + iblk * 64 + w * 16) * Dd;
    const short* B = Kb + ((size_t)bh * Nn + jblk * 64) * Dd;
    f32x4 acc[4] = {};
    mfma_tile_16x64(A, Dd, B, Dd, Dd, lane, acc);
#pragma unroll
    for (int nf = 0; nf < 4; ++nf) {
#pragma unroll
        for (int r = 0; r < 4; ++r) {
            int il = iblk * 64 + w * 16 + ((lane >> 4) * 4) + r;
            int j = jblk * 64 + nf * 16 + (lane & 15);
            attnC[((size_t)bh * ICH + il) * Nn + j] = f2bf(acc[nf][r] * 0.125f);
        }
    }
}

// ---------------------------------------------------------------------------
// K3b: in-place row softmax over j (2048). One block per chunk row.
// ---------------------------------------------------------------------------
__global__ __launch_bounds__(256) void k_softmax(short* __restrict__ attnC) {
    size_t row = blockIdx.x;
    short* p = attnC + row * Nn;
    int tid = threadIdx.x;
    int w = tid >> 6, lane = tid & 63;
    __shared__ float red[4];
    bf16x8 v = *(bf16x8*)(p + tid * 8);
    float f[8];
#pragma unroll
    for (int t = 0; t < 8; ++t) f[t] = bf2f(v[t]);
    float m = f[0];
#pragma unroll
    for (int t = 1; t < 8; ++t) m = fmaxf(m, f[t]);
#pragma unroll
    for (int off = 32; off >= 1; off >>= 1) m = fmaxf(m, __shfl_xor(m, off));
    if (lane == 0) red[w] = m;
    __syncthreads();
    m = fmaxf(fmaxf(red[0], red[1]), fmaxf(red[2], red[3]));
    __syncthreads();
    float s = 0.f;
#pragma unroll
    for (int t = 0; t < 8; ++t) { f[t] = __expf(f[t] - m); s += f[t]; }
#pragma unroll
    for (int off = 32; off >= 1; off >>= 1) s += __shfl_xor(s, off);
    if (lane == 0) red[w] = s;
    __syncthreads();
    s = red[0] + red[1] + red[2] + red[3];
    float inv = 1.0f / s;
#pragma unroll
    for (int t = 0; t < 8; ++t) v[t] = f2bf(f[t] * inv);
    *(bf16x8*)(p + tid * 8) = v;
}

// ---------------------------------------------------------------------------
// K4: in-place cross-head mix (8x8) + LayerNorm over head axis (chunk).
// Each thread owns 8 consecutive j for one (b, il), across all 8 heads.
// ---------------------------------------------------------------------------
__global__ __launch_bounds__(256) void k_mixln(short* __restrict__ attnC,
                                               const float* __restrict__ R,
                                               const float* __restrict__ rg,
                                               const float* __restrict__ rb,
                                               int ICH, int ishift) {
    __shared__ float Rs[64], rgs[8], rbs[8];
    int tid = threadIdx.x;
    if (tid < 64) Rs[tid] = R[tid];
    if (tid < 8) { rgs[tid] = rg[tid]; rbs[tid] = rb[tid]; }
    __syncthreads();
    size_t idx = (size_t)blockIdx.x * 256 + tid;  // over 4*ICH*256
    int j8 = (int)(idx & 255) << 3;
    int il = (int)((idx >> 8) & (size_t)(ICH - 1));
    int b = (int)(idx >> (8 + ishift));
    const size_t hs = (size_t)ICH * Nn;
    size_t base = ((size_t)(b * Hh) * ICH + il) * Nn + j8;
    float a[8][8];
#pragma unroll
    for (int h = 0; h < 8; ++h) {
        bf16x8 v = *(bf16x8*)(attnC + base + h * hs);
#pragma unroll
        for (int t = 0; t < 8; ++t) a[h][t] = bf2f(v[t]);
    }
    short o[8][8];  // [g][t]
#pragma unroll
    for (int t = 0; t < 8; ++t) {
        float ap[8];
#pragma unroll
        for (int gg = 0; gg < 8; ++gg) {
            float s = 0.f;
#pragma unroll
            for (int h = 0; h < 8; ++h) s += a[h][t] * Rs[h * 8 + gg];
            ap[gg] = s;
        }
        float mu = 0.f;
#pragma unroll
        for (int gg = 0; gg < 8; ++gg) mu += ap[gg];
        mu *= 0.125f;
        float var = 0.f;
#pragma unroll
        for (int gg = 0; gg < 8; ++gg) {
            float d = ap[gg] - mu;
            var += d * d;
        }
        var *= 0.125f;
        float rs = rsqrtf(var + 1e-5f);
#pragma unroll
        for (int gg = 0; gg < 8; ++gg)
            o[gg][t] = f2bf((ap[gg] - mu) * rs * rgs[gg] + rbs[gg]);
    }
#pragma unroll
    for (int gg = 0; gg < 8; ++gg) {
        bf16x8 v;
#pragma unroll
        for (int t = 0; t < 8; ++t) v[t] = o[gg][t];
        *(bf16x8*)(attnC + base + gg * hs) = v;
    }
}

// ---------------------------------------------------------------------------
// K5: out_h = attn'' @ V per (b,g) for an i-chunk. B = Vt (j-contig).
// ---------------------------------------------------------------------------
__global__ __launch_bounds__(256) void k_pv(const short* __restrict__ attnC,
                                            const short* __restrict__ Vt,
                                            short* __restrict__ outh,
                                            int i0, int ICH) {
    int iblk = blockIdx.x, bg = blockIdx.y;
    int b = bg >> 3, g = bg & 7;
    int w = threadIdx.x >> 6, lane = threadIdx.x & 63;
    const short* A = attnC + ((size_t)bg * ICH + iblk * 64 + w * 16) * Nn;
    const short* B = Vt + (size_t)bg * Dd * Nn;
    f32x4 acc[4] = {};
    mfma_tile_16x64(A, Nn, B, Nn, Nn, lane, acc);
#pragma unroll
    for (int nf = 0; nf < 4; ++nf) {
#pragma unroll
        for (int r = 0; r < 4; ++r) {
            int i = i0 + iblk * 64 + w * 16 + ((lane >> 4) * 4) + r;
            int dd = nf * 16 + (lane & 15);
            outh[((size_t)b * Nn + i) * 512 + g * 64 + dd] = f2bf(acc[nf][r]);
        }
    }
}

// ---------------------------------------------------------------------------
// K6: final = out_h @ w_outT^T + b_out, f32 output.
// ---------------------------------------------------------------------------
__global__ __launch_bounds__(256) void k_out(const short* __restrict__ outh,
                                             const short* __restrict__ wT,
                                             const float* __restrict__ bias,
                                             float* __restrict__ out) {
    int i0 = blockIdx.x * 64, n0 = blockIdx.y * 64;
    int w = threadIdx.x >> 6, lane = threadIdx.x & 63;
    f32x4 acc[4] = {};
    const short* A = outh + (size_t)(i0 + w * 16) * 512;
    const short* B = wT + (size_t)n0 * 512;
    mfma_tile_16x64(A, 512, B, 512, 512, lane, acc);
#pragma unroll
    for (int nf = 0; nf < 4; ++nf) {
#pragma unroll
        for (int r = 0; r < 4; ++r) {
            int row = i0 + w * 16 + ((lane >> 4) * 4) + r;
            int c = n0 + nf * 16 + (lane & 15);
            out[(size_t)row * 512 + c] = acc[nf][r] + bias[c];
        }
    }
}

extern "C" void kernel_launch(void* const* d_in, const int* in_sizes, int n_in,
                              void* d_out, int out_size, void* d_ws, size_t ws_size,
                              hipStream_t stream) {
    const float* x      = (const float*)d_in[0];
    const float* ln_g   = (const float*)d_in[1];
    const float* ln_b   = (const float*)d_in[2];
    const float* w_qkv  = (const float*)d_in[3];
    const float* reattn = (const float*)d_in[4];
    const float* rn_g   = (const float*)d_in[5];
    const float* rn_b   = (const float*)d_in[6];
    const float* w_out  = (const float*)d_in[7];
    const float* b_out  = (const float*)d_in[8];
    float* out = (float*)d_out;

    char* ws = (char*)d_ws;
    short* wqkvT = (short*)ws; ws += (size_t)1536 * 512 * 2;   //  1.50 MB
    short* woutT = (short*)ws; ws += (size_t)512 * 512 * 2;    //  0.50 MB
    short* xn    = (short*)ws; ws += (size_t)8192 * 512 * 2;   //  8.39 MB
    short* Q     = (short*)ws; ws += (size_t)32 * 2048 * 64 * 2;
    short* Kb    = (short*)ws; ws += (size_t)32 * 2048 * 64 * 2;
    short* Vt    = (short*)ws; ws += (size_t)32 * 64 * 2048 * 2;
    short* outh  = (short*)ws; ws += (size_t)8192 * 512 * 2;
    size_t fixed_bytes = (size_t)(ws - (char*)d_ws);
    short* attnC = (short*)ws;  // chunk buffer, sized below

    // Adaptive i-chunk: largest power-of-two ICH (64..2048) whose
    // [32][ICH][2048] bf16 chunk fits in the remaining workspace.
    int ICH = 2048;
    while (ICH > 64 &&
           fixed_bytes + (size_t)32 * ICH * Nn * 2 > ws_size) ICH >>= 1;
    int ishift = 0;
    for (int t = ICH; t > 1; t >>= 1) ++ishift;  // log2(ICH)

    // K0: weight transpose+cast
    k_transpose_cast<<<(512 * 1536 + 255) / 256, 256, 0, stream>>>(w_qkv, wqkvT, 512, 1536);
    k_transpose_cast<<<(512 * 512 + 255) / 256, 256, 0, stream>>>(w_out, woutT, 512, 512);

    // K1: LayerNorm + cast
    k_ln<<<8192 / 4, 256, 0, stream>>>(x, ln_g, ln_b, xn);

    // K2: QKV projection GEMM
    k_qkv<<<dim3(8192 / 64, 1536 / 64), 256, 0, stream>>>(xn, wqkvT, Q, Kb, Vt);

    // K3..K5 per i-chunk
    for (int i0 = 0; i0 < Nn; i0 += ICH) {
        k_scores<<<dim3(ICH / 64, Nn / 64, 32), 256, 0, stream>>>(Q, Kb, attnC, i0, ICH);
        k_softmax<<<32 * ICH, 256, 0, stream>>>(attnC);
        k_mixln<<<4 * ICH, 256, 0, stream>>>(attnC, reattn, rn_g, rn_b, ICH, ishift);
        k_pv<<<dim3(ICH / 64, 32), 256, 0, stream>>>(attnC, Vt, outh, i0, ICH);
    }

    // K6: output projection + bias
    k_out<<<dim3(8192 / 64, 512 / 64), 256, 0, stream>>>(outh, woutT, b_out, out);
}

// Round 3
// 487.753 us; speedup vs baseline: 1.4165x; 1.4165x over previous
//
#include <hip/hip_runtime.h>
#include <hip/hip_bf16.h>
#include <math.h>

#define DEV __device__ __forceinline__

typedef short bf16x8 __attribute__((ext_vector_type(8)));
typedef float f32x4 __attribute__((ext_vector_type(4)));

static const int Nn = 2048;
static const int DIMd = 512;

DEV float bf2f(short u) {
    union { unsigned int i; float f; } c;
    c.i = ((unsigned int)(unsigned short)u) << 16;
    return c.f;
}

DEV short f2bf(float f) {
    union { float f; unsigned int i; } c;
    c.f = f;
    unsigned int u = c.i;
    unsigned int r = (u + 0x7fffu + ((u >> 16) & 1u)) >> 16;
    return (short)r;
}

// async global->LDS, 16B per lane (lane-linear LDS dest required)
DEV void gload16(const short* __restrict__ g, short* l) {
    __builtin_amdgcn_global_load_lds(
        (__attribute__((address_space(1))) void*)g,
        (__attribute__((address_space(3))) void*)l, 16, 0, 0);
}

// ---------------------------------------------------------------------------
// K0: transpose + cast f32 [K][N] -> bf16 [N][K]
// ---------------------------------------------------------------------------
__global__ void k_transpose_cast(const float* __restrict__ src,
                                 short* __restrict__ dst, int K, int N) {
    int o = blockIdx.x * 256 + threadIdx.x;
    if (o >= K * N) return;
    int n = o / K, k = o - n * K;
    dst[o] = f2bf(src[(size_t)k * N + n]);
}

// ---------------------------------------------------------------------------
// K1: row LayerNorm over DIM=512, f32 in -> bf16 out. One wave per row.
// ---------------------------------------------------------------------------
__global__ __launch_bounds__(256) void k_ln(const float* __restrict__ x,
                                            const float* __restrict__ g,
                                            const float* __restrict__ bta,
                                            short* __restrict__ xn) {
    int row = blockIdx.x * 4 + (threadIdx.x >> 6);
    int lane = threadIdx.x & 63;
    const float* xr = x + (size_t)row * DIMd;
    float4 v0 = ((const float4*)xr)[lane * 2];
    float4 v1 = ((const float4*)xr)[lane * 2 + 1];
    float f[8] = {v0.x, v0.y, v0.z, v0.w, v1.x, v1.y, v1.z, v1.w};
    float s = 0.f, sq = 0.f;
#pragma unroll
    for (int t = 0; t < 8; ++t) { s += f[t]; sq += f[t] * f[t]; }
#pragma unroll
    for (int off = 32; off >= 1; off >>= 1) {
        s += __shfl_xor(s, off);
        sq += __shfl_xor(sq, off);
    }
    float mu = s * (1.0f / 512.0f);
    float var = sq * (1.0f / 512.0f) - mu * mu;
    float rs = rsqrtf(var + 1e-5f);
    bf16x8 o;
#pragma unroll
    for (int t = 0; t < 8; ++t) {
        int c = lane * 8 + t;
        o[t] = f2bf((f[t] - mu) * rs * g[c] + bta[c]);
    }
    *(bf16x8*)(xn + (size_t)row * DIMd + lane * 8) = o;
}

// ---------------------------------------------------------------------------
// m97-style 128x128 tile GEMM main loop. A [M][K], B^T [N][K], both k-contig.
// 4 waves in 2x2 quadrants, 4x4 16x16 fragments each, BK=64, LDS staged via
// global_load_lds (lane-linear dest), 2-barrier loop.
// ---------------------------------------------------------------------------
DEV void gemm128_loop(const short* __restrict__ A, const short* __restrict__ B,
                      int K, int i0, int n0, int tid,
                      short* As, short* Bs, f32x4 acc[4][4]) {
    const int w = tid >> 6, wr = w >> 1, wc = w & 1;
    const int lane = tid & 63, fr = lane & 15, fq = lane >> 4;
    const int sr = tid >> 3, sc = (tid & 7) * 8;  // staging row / col(element)
    for (int k0 = 0; k0 < K; k0 += 64) {
#pragma unroll
        for (int L = 0; L < 4; ++L) {
            gload16(A + (size_t)(i0 + L * 32 + sr) * K + k0 + sc,
                    As + (L * 32 + sr) * 64 + sc);
            gload16(B + (size_t)(n0 + L * 32 + sr) * K + k0 + sc,
                    Bs + (L * 32 + sr) * 64 + sc);
        }
        __syncthreads();
#pragma unroll
        for (int kk = 0; kk < 2; ++kk) {
            bf16x8 af[4], bfr[4];
#pragma unroll
            for (int m = 0; m < 4; ++m)
                af[m] = *(const bf16x8*)(As + (wr * 64 + m * 16 + fr) * 64 + kk * 32 + fq * 8);
#pragma unroll
            for (int n = 0; n < 4; ++n)
                bfr[n] = *(const bf16x8*)(Bs + (wc * 64 + n * 16 + fr) * 64 + kk * 32 + fq * 8);
#pragma unroll
            for (int m = 0; m < 4; ++m)
#pragma unroll
                for (int n = 0; n < 4; ++n)
                    acc[m][n] = __builtin_amdgcn_mfma_f32_16x16x32_bf16(af[m], bfr[n], acc[m][n], 0, 0, 0);
        }
        __syncthreads();
    }
}

// ---------------------------------------------------------------------------
// K2: qkv = xn @ w_qkvT^T. M=8192, N=1536, K=512; scatter epilogue.
// ---------------------------------------------------------------------------
__global__ __launch_bounds__(256) void k_qkv(const short* __restrict__ xn,
                                             const short* __restrict__ wT,
                                             short* __restrict__ Q,
                                             short* __restrict__ Kb,
                                             short* __restrict__ Vt) {
    __shared__ short As[128 * 64], Bs[128 * 64];
    int tid = threadIdx.x;
    int i0 = blockIdx.x * 128, n0 = blockIdx.y * 128;
    f32x4 acc[4][4] = {};
    gemm128_loop(xn, wT, DIMd, i0, n0, tid, As, Bs, acc);
    const int w = tid >> 6, wr = w >> 1, wc = w & 1;
    const int lane = tid & 63, fr = lane & 15, fq = lane >> 4;
#pragma unroll
    for (int m = 0; m < 4; ++m) {
#pragma unroll
        for (int n = 0; n < 4; ++n) {
#pragma unroll
            for (int r = 0; r < 4; ++r) {
                int row = i0 + wr * 64 + m * 16 + fq * 4 + r;  // [0,8192)
                int c = n0 + wc * 64 + n * 16 + fr;            // [0,1536)
                short hv = f2bf(acc[m][n][r]);
                int b = row >> 11, i = row & 2047;
                int t = c >> 9, rem = c & 511;
                int h = rem >> 6, dd = rem & 63;
                size_t bh = (size_t)(b * 8 + h);
                if (t == 0)      Q [(bh * Nn + i) * 64 + dd] = hv;
                else if (t == 1) Kb[(bh * Nn + i) * 64 + dd] = hv;
                else             Vt[(bh * 64 + dd) * Nn + i] = hv;
            }
        }
    }
}

// ---------------------------------------------------------------------------
// K6: final = out_h @ w_outT^T + b_out. M=8192, N=512, K=512. f32 out.
// ---------------------------------------------------------------------------
__global__ __launch_bounds__(256) void k_out(const short* __restrict__ outh,
                                             const short* __restrict__ wT,
                                             const float* __restrict__ bias,
                                             float* __restrict__ out) {
    __shared__ short As[128 * 64], Bs[128 * 64];
    int tid = threadIdx.x;
    int i0 = blockIdx.x * 128, n0 = blockIdx.y * 128;
    f32x4 acc[4][4] = {};
    gemm128_loop(outh, wT, 512, i0, n0, tid, As, Bs, acc);
    const int w = tid >> 6, wr = w >> 1, wc = w & 1;
    const int lane = tid & 63, fr = lane & 15, fq = lane >> 4;
#pragma unroll
    for (int m = 0; m < 4; ++m)
#pragma unroll
        for (int n = 0; n < 4; ++n)
#pragma unroll
            for (int r = 0; r < 4; ++r) {
                int row = i0 + wr * 64 + m * 16 + fq * 4 + r;
                int c = n0 + wc * 64 + n * 16 + fr;
                out[(size_t)row * 512 + c] = acc[m][n][r] + bias[c];
            }
}

// ---------------------------------------------------------------------------
// K3: S = Q K^T * scale. Block: 64 i x 128 j, 4 waves 2x2, acc[2][4]. K=64.
// ---------------------------------------------------------------------------
__global__ __launch_bounds__(256) void k_scores(const short* __restrict__ Q,
                                                const short* __restrict__ Kb,
                                                short* __restrict__ attnC,
                                                int i0, int ICH) {
    int iblk = blockIdx.x, j0 = blockIdx.y * 128, bh = blockIdx.z;
    int tid = threadIdx.x;
    const int w = tid >> 6, wi = w >> 1, wj = w & 1;
    const int lane = tid & 63, fr = lane & 15, fq = lane >> 4;
    const short* A = Q + ((size_t)bh * Nn + i0 + iblk * 64 + wi * 32) * 64;
    const short* B = Kb + ((size_t)bh * Nn + j0 + wj * 64) * 64;
    f32x4 acc[2][4] = {};
#pragma unroll
    for (int kk = 0; kk < 2; ++kk) {
        bf16x8 af[2], bfr[4];
#pragma unroll
        for (int m = 0; m < 2; ++m)
            af[m] = *(const bf16x8*)(A + (m * 16 + fr) * 64 + kk * 32 + fq * 8);
#pragma unroll
        for (int n = 0; n < 4; ++n)
            bfr[n] = *(const bf16x8*)(B + (n * 16 + fr) * 64 + kk * 32 + fq * 8);
#pragma unroll
        for (int m = 0; m < 2; ++m)
#pragma unroll
            for (int n = 0; n < 4; ++n)
                acc[m][n] = __builtin_amdgcn_mfma_f32_16x16x32_bf16(af[m], bfr[n], acc[m][n], 0, 0, 0);
    }
#pragma unroll
    for (int m = 0; m < 2; ++m)
#pragma unroll
        for (int n = 0; n < 4; ++n)
#pragma unroll
            for (int r = 0; r < 4; ++r) {
                int il = iblk * 64 + wi * 32 + m * 16 + fq * 4 + r;
                int j = j0 + wj * 64 + n * 16 + fr;
                attnC[((size_t)bh * ICH + il) * Nn + j] = f2bf(acc[m][n][r] * 0.125f);
            }
}

// ---------------------------------------------------------------------------
// K4: fused softmax (over j) + cross-head mix + head-LN, in place.
// One block per (b, il); thread owns 8 j for all 8 heads.
// ---------------------------------------------------------------------------
__global__ __launch_bounds__(256) void k_smx(short* __restrict__ attnC,
                                             const float* __restrict__ R,
                                             const float* __restrict__ rg,
                                             const float* __restrict__ rb,
                                             int ICH, int ishift) {
    __shared__ float Rs[64], rgs[8], rbs[8];
    __shared__ float redm[4][8], reds[4][8];
    int tid = threadIdx.x, w = tid >> 6, lane = tid & 63;
    if (tid < 64) Rs[tid] = R[tid];
    if (tid < 8) { rgs[tid] = rg[tid]; rbs[tid] = rb[tid]; }
    int il = blockIdx.x & (ICH - 1);
    int b = blockIdx.x >> ishift;
    const size_t hs = (size_t)ICH * Nn;
    size_t base = ((size_t)(b * 8) * ICH + il) * Nn + tid * 8;
    float a[8][8];
#pragma unroll
    for (int h = 0; h < 8; ++h) {
        bf16x8 v = *(bf16x8*)(attnC + base + h * hs);
#pragma unroll
        for (int t = 0; t < 8; ++t) a[h][t] = bf2f(v[t]);
    }
    // per-head row max
    float mx[8];
#pragma unroll
    for (int h = 0; h < 8; ++h) {
        float m = a[h][0];
#pragma unroll
        for (int t = 1; t < 8; ++t) m = fmaxf(m, a[h][t]);
#pragma unroll
        for (int off = 32; off >= 1; off >>= 1) m = fmaxf(m, __shfl_xor(m, off));
        mx[h] = m;
    }
    if (lane == 0) {
#pragma unroll
        for (int h = 0; h < 8; ++h) redm[w][h] = mx[h];
    }
    __syncthreads();
#pragma unroll
    for (int h = 0; h < 8; ++h)
        mx[h] = fmaxf(fmaxf(redm[0][h], redm[1][h]), fmaxf(redm[2][h], redm[3][h]));
    // exp + per-head sum
    float sm[8];
#pragma unroll
    for (int h = 0; h < 8; ++h) {
        float s = 0.f;
#pragma unroll
        for (int t = 0; t < 8; ++t) { a[h][t] = __expf(a[h][t] - mx[h]); s += a[h][t]; }
#pragma unroll
        for (int off = 32; off >= 1; off >>= 1) s += __shfl_xor(s, off);
        sm[h] = s;
    }
    if (lane == 0) {
#pragma unroll
        for (int h = 0; h < 8; ++h) reds[w][h] = sm[h];
    }
    __syncthreads();
#pragma unroll
    for (int h = 0; h < 8; ++h) {
        float s = reds[0][h] + reds[1][h] + reds[2][h] + reds[3][h];
        sm[h] = 1.0f / s;
    }
    // p = a*inv (f32), mix across heads, LN over head axis, write bf16
    short o[8][8];
#pragma unroll
    for (int t = 0; t < 8; ++t) {
        float ap[8];
#pragma unroll
        for (int gg = 0; gg < 8; ++gg) {
            float s = 0.f;
#pragma unroll
            for (int h = 0; h < 8; ++h) s += (a[h][t] * sm[h]) * Rs[h * 8 + gg];
            ap[gg] = s;
        }
        float mu = 0.f;
#pragma unroll
        for (int gg = 0; gg < 8; ++gg) mu += ap[gg];
        mu *= 0.125f;
        float var = 0.f;
#pragma unroll
        for (int gg = 0; gg < 8; ++gg) { float d = ap[gg] - mu; var += d * d; }
        var *= 0.125f;
        float rs = rsqrtf(var + 1e-5f);
#pragma unroll
        for (int gg = 0; gg < 8; ++gg)
            o[gg][t] = f2bf((ap[gg] - mu) * rs * rgs[gg] + rbs[gg]);
    }
#pragma unroll
    for (int gg = 0; gg < 8; ++gg) {
        bf16x8 v;
#pragma unroll
        for (int t = 0; t < 8; ++t) v[t] = o[gg][t];
        *(bf16x8*)(attnC + base + gg * hs) = v;
    }
}

// ---------------------------------------------------------------------------
// K5a: PV partials. Grid (ICH/64, 32 bg, NS). Block: 64 i x 64 d; 4 waves
// split this block's j-slice; LDS-reduce wave partials; f32 partial out.
// ---------------------------------------------------------------------------
__global__ __launch_bounds__(256) void k_pv_part(const short* __restrict__ attnC,
                                                 const short* __restrict__ Vt,
                                                 float* __restrict__ part,
                                                 int ICH, int NS) {
    __shared__ float red[4 * 4096];  // 64 KB
    int iblk = blockIdx.x, bg = blockIdx.y, ks = blockIdx.z;
    int tid = threadIdx.x;
    const int w = tid >> 6, lane = tid & 63, fr = lane & 15, fq = lane >> 4;
    const int JS = Nn / NS, JW = JS / 4;
    const short* A = attnC + ((size_t)bg * ICH + iblk * 64) * Nn + ks * JS + w * JW;
    const short* B = Vt + (size_t)bg * 64 * Nn + ks * JS + w * JW;
    f32x4 acc[4][4] = {};
    for (int j = 0; j < JW; j += 32) {
        bf16x8 af[4], bfr[4];
#pragma unroll
        for (int m = 0; m < 4; ++m)
            af[m] = *(const bf16x8*)(A + (size_t)(m * 16 + fr) * Nn + j + fq * 8);
#pragma unroll
        for (int n = 0; n < 4; ++n)
            bfr[n] = *(const bf16x8*)(B + (size_t)(n * 16 + fr) * Nn + j + fq * 8);
#pragma unroll
        for (int m = 0; m < 4; ++m)
#pragma unroll
            for (int n = 0; n < 4; ++n)
                acc[m][n] = __builtin_amdgcn_mfma_f32_16x16x32_bf16(af[m], bfr[n], acc[m][n], 0, 0, 0);
    }
#pragma unroll
    for (int m = 0; m < 4; ++m)
#pragma unroll
        for (int n = 0; n < 4; ++n)
#pragma unroll
            for (int r = 0; r < 4; ++r)
                red[w * 4096 + (m * 16 + fq * 4 + r) * 64 + n * 16 + fr] = acc[m][n][r];
    __syncthreads();
    for (int e = tid; e < 4096; e += 256) {
        float s = red[e] + red[4096 + e] + red[8192 + e] + red[12288 + e];
        int il = iblk * 64 + (e >> 6), dd = e & 63;
        part[(((size_t)ks * 32 + bg) * ICH + il) * 64 + dd] = s;
    }
}

// ---------------------------------------------------------------------------
// K5b: reduce NS partials -> outh bf16 [b][i][g*64+d]
// ---------------------------------------------------------------------------
__global__ __launch_bounds__(256) void k_pv_reduce(const float* __restrict__ part,
                                                   short* __restrict__ outh,
                                                   int ICH, int NS, int i0, int ishift) {
    int idx = blockIdx.x * 256 + threadIdx.x;  // < 32*ICH*64
    int dd = idx & 63;
    int il = (idx >> 6) & (ICH - 1);
    int bg = idx >> (6 + ishift);
    float s = 0.f;
    for (int ks = 0; ks < NS; ++ks)
        s += part[(((size_t)ks * 32 + bg) * ICH + il) * 64 + dd];
    int b = bg >> 3, g = bg & 7;
    outh[((size_t)b * Nn + i0 + il) * 512 + g * 64 + dd] = f2bf(s);
}

extern "C" void kernel_launch(void* const* d_in, const int* in_sizes, int n_in,
                              void* d_out, int out_size, void* d_ws, size_t ws_size,
                              hipStream_t stream) {
    const float* x      = (const float*)d_in[0];
    const float* ln_g   = (const float*)d_in[1];
    const float* ln_b   = (const float*)d_in[2];
    const float* w_qkv  = (const float*)d_in[3];
    const float* reattn = (const float*)d_in[4];
    const float* rn_g   = (const float*)d_in[5];
    const float* rn_b   = (const float*)d_in[6];
    const float* w_out  = (const float*)d_in[7];
    const float* b_out  = (const float*)d_in[8];
    float* out = (float*)d_out;

    char* ws = (char*)d_ws;
    short* wqkvT = (short*)ws; ws += (size_t)1536 * 512 * 2;
    short* woutT = (short*)ws; ws += (size_t)512 * 512 * 2;
    short* xn    = (short*)ws; ws += (size_t)8192 * 512 * 2;   // 8.39 MB; dead after k_qkv
    short* Q     = (short*)ws; ws += (size_t)32 * 2048 * 64 * 2;
    short* Kb    = (short*)ws; ws += (size_t)32 * 2048 * 64 * 2;
    short* Vt    = (short*)ws; ws += (size_t)32 * 64 * 2048 * 2;
    short* outh  = (short*)ws; ws += (size_t)8192 * 512 * 2;
    size_t fixed_bytes = (size_t)(ws - (char*)d_ws);
    short* attnC = (short*)ws;
    float* pvpart = (float*)xn;  // alias: NS*32*ICH*64*4 = 8.39 MB always

    // i-chunk: largest power-of-two ICH in [64,1024] that fits
    int ICH = 1024;
    while (ICH > 64 && fixed_bytes + (size_t)32 * ICH * Nn * 2 > ws_size) ICH >>= 1;
    int ishift = 0;
    for (int t = ICH; t > 1; t >>= 1) ++ishift;
    int NS = 1024 / ICH;  // K-split slices for PV; NS*ICH == 1024

    k_transpose_cast<<<(512 * 1536 + 255) / 256, 256, 0, stream>>>(w_qkv, wqkvT, 512, 1536);
    k_transpose_cast<<<(512 * 512 + 255) / 256, 256, 0, stream>>>(w_out, woutT, 512, 512);
    k_ln<<<8192 / 4, 256, 0, stream>>>(x, ln_g, ln_b, xn);
    k_qkv<<<dim3(8192 / 128, 1536 / 128), 256, 0, stream>>>(xn, wqkvT, Q, Kb, Vt);

    for (int i0 = 0; i0 < Nn; i0 += ICH) {
        k_scores<<<dim3(ICH / 64, Nn / 128, 32), 256, 0, stream>>>(Q, Kb, attnC, i0, ICH);
        k_smx<<<4 * ICH, 256, 0, stream>>>(attnC, reattn, rn_g, rn_b, ICH, ishift);
        k_pv_part<<<dim3(ICH / 64, 32, NS), 256, 0, stream>>>(attnC, Vt, pvpart, ICH, NS);
        k_pv_reduce<<<8 * ICH, 256, 0, stream>>>(pvpart, outh, ICH, NS, i0, ishift);
    }

    k_out<<<dim3(8192 / 128, 512 / 128), 256, 0, stream>>>(outh, woutT, b_out, out);
}